// Round 2
// baseline (1412.773 us; speedup 1.0000x reference)
//
#include <hip/hip_runtime.h>
#include <hip/hip_bf16.h>
#include <cstdint>

// Problem dims (fixed): B=2, S=2048, E=1024, H=16, D=64
#define PB 2
#define PS 2048
#define PE 1024
#define PH 16
#define PD 64

typedef __attribute__((ext_vector_type(8))) short short8;
typedef __attribute__((ext_vector_type(8))) ushort u16x8;
typedef __attribute__((ext_vector_type(4))) float f32x4;

static __device__ __forceinline__ float bf2f(ushort u) {
  return __uint_as_float(((unsigned)u) << 16);
}
static __device__ __forceinline__ ushort f2bf(float f) {
  unsigned u = __float_as_uint(f);
  u += 0x7fffu + ((u >> 16) & 1u);   // RNE
  return (ushort)(u >> 16);
}

// CK-idiom async global->LDS 16B copy. LDS dest must be wave-uniform base.
static __device__ __forceinline__ void async16(void* lds, const void* g) {
  __attribute__((address_space(3))) unsigned* l =
      reinterpret_cast<__attribute__((address_space(3))) unsigned*>(
          reinterpret_cast<uintptr_t>(lds));
  const __attribute__((address_space(1))) unsigned* gp =
      reinterpret_cast<const __attribute__((address_space(1))) unsigned*>(
          reinterpret_cast<uintptr_t>(g));
  __builtin_amdgcn_global_load_lds(gp, l, 16, 0, 0);
}

// ---------------------------------------------------------------------------
// fp32 -> bf16 pre-conversion. blockIdx.y selects tensor.
// ---------------------------------------------------------------------------
__global__ __launch_bounds__(256)
void cvt_kernel(const float* __restrict__ s0, const float* __restrict__ s1,
                const float* __restrict__ s2, const float* __restrict__ s3,
                const float* __restrict__ s4, const float* __restrict__ s5,
                const float* __restrict__ s6,
                ushort* d0, ushort* d1, ushort* d2, ushort* d3, ushort* d4,
                ushort* d5, ushort* d6) {
  const int t = blockIdx.y;
  const float* src = t == 0 ? s0 : t == 1 ? s1 : t == 2 ? s2 : t == 3 ? s3
                   : t == 4 ? s4 : t == 5 ? s5 : s6;
  ushort* dst = t == 0 ? d0 : t == 1 ? d1 : t == 2 ? d2 : t == 3 ? d3
              : t == 4 ? d4 : t == 5 ? d5 : d6;
  const size_t n = (t < 3) ? (size_t)4194304 : (size_t)1048576;
  const size_t i0 = ((size_t)blockIdx.x * 256 + threadIdx.x) * 8;
  if (i0 >= n) return;
  const f32x4 a = *(const f32x4*)(src + i0);
  const f32x4 b = *(const f32x4*)(src + i0 + 4);
  u16x8 o;
  o[0] = f2bf(a[0]); o[1] = f2bf(a[1]); o[2] = f2bf(a[2]); o[3] = f2bf(a[3]);
  o[4] = f2bf(b[0]); o[5] = f2bf(b[1]); o[6] = f2bf(b[2]); o[7] = f2bf(b[3]);
  *(u16x8*)(dst + i0) = o;
}

// ---------------------------------------------------------------------------
// GEMM core (m97 structure): C[128x128] += A[M,K] * W[N,K]^T over K=1024.
// BM=BN=128, BK=32, 256 threads = 4 waves in 2x2, each wave 64x64 via 4x4
// mfma_f32_16x16x32_bf16. A,W bf16 row-major with K contiguous.
// ---------------------------------------------------------------------------
__device__ __forceinline__ void gemm_core(const ushort* __restrict__ A,
                                          const ushort* __restrict__ W,
                                          int m0, int n0,
                                          ushort* As, ushort* Bs,
                                          f32x4 acc[4][4]) {
  const int tid  = threadIdx.x;
  const int wave = tid >> 6;
  const int lane = tid & 63;
  const int quad = lane >> 4;
  const int lrow = lane & 15;
  const int wm = wave >> 1;
  const int wn = wave & 1;
  const int row0 = tid >> 2;         // 0..63
  const int kc8  = (tid & 3) * 8;    // k element offset within BK

  for (int kt = 0; kt < PE; kt += 32) {
    async16(As + (size_t)wave * 512,        A + (size_t)(m0 + row0)      * PE + kt + kc8);
    async16(As + 2048 + (size_t)wave * 512, A + (size_t)(m0 + row0 + 64) * PE + kt + kc8);
    async16(Bs + (size_t)wave * 512,        W + (size_t)(n0 + row0)      * PE + kt + kc8);
    async16(Bs + 2048 + (size_t)wave * 512, W + (size_t)(n0 + row0 + 64) * PE + kt + kc8);
    __syncthreads();   // vmcnt(0) drain + barrier: staged data visible
    short8 af[4], bf[4];
#pragma unroll
    for (int i = 0; i < 4; ++i) {
      af[i] = *(const short8*)(As + (wm * 64 + i * 16 + lrow) * 32 + quad * 8);
      bf[i] = *(const short8*)(Bs + (wn * 64 + i * 16 + lrow) * 32 + quad * 8);
    }
#pragma unroll
    for (int i = 0; i < 4; ++i)
#pragma unroll
      for (int j = 0; j < 4; ++j)
        acc[i][j] = __builtin_amdgcn_mfma_f32_16x16x32_bf16(af[i], bf[j], acc[i][j], 0, 0, 0);
    __syncthreads();   // all reads done before next stage overwrites
  }
}

// ---------------------------------------------------------------------------
// Fused QKV projection (bf16-converted inputs). Writes bf16 [B,H,S,D].
// ---------------------------------------------------------------------------
__global__ __launch_bounds__(256)
void qkv_kernel(const ushort* __restrict__ q, const ushort* __restrict__ k,
                const ushort* __restrict__ v,
                const ushort* __restrict__ Wq, const ushort* __restrict__ Wk,
                const ushort* __restrict__ Wv,
                const float* __restrict__ bq, const float* __restrict__ bk,
                const float* __restrict__ bv,
                ushort* __restrict__ qh, ushort* __restrict__ kh,
                ushort* __restrict__ vh) {
  __shared__ __align__(16) ushort As[128 * 32];
  __shared__ __align__(16) ushort Bs[128 * 32];
  const int which = blockIdx.x >> 3;
  const int n0 = (blockIdx.x & 7) * 128;
  const int m0 = blockIdx.y * 128;
  const ushort* A  = which == 0 ? q  : (which == 1 ? k  : v);
  const ushort* W  = which == 0 ? Wq : (which == 1 ? Wk : Wv);
  const float* bi  = which == 0 ? bq : (which == 1 ? bk : bv);
  ushort* Out      = which == 0 ? qh : (which == 1 ? kh : vh);

  f32x4 acc[4][4] = {};
  gemm_core(A, W, m0, n0, As, Bs, acc);

  const int lane = threadIdx.x & 63;
  const int wave = threadIdx.x >> 6;
  const int quad = lane >> 4, lrow = lane & 15;
  const int wm = wave >> 1, wn = wave & 1;
#pragma unroll
  for (int j = 0; j < 4; ++j) {
    const int col = n0 + wn * 64 + j * 16 + lrow;          // n in [0,1024)
    const float bias = bi[col];
    const int h = col >> 6, d = col & 63;
#pragma unroll
    for (int i = 0; i < 4; ++i)
#pragma unroll
      for (int r = 0; r < 4; ++r) {
        const int row = m0 + wm * 64 + i * 16 + quad * 4 + r;  // m in [0,4096)
        const int b = row >> 11, s = row & 2047;
        Out[((size_t)((b << 4) + h) << 17) + ((size_t)s << 6) + d] =
            f2bf(acc[i][j][r] + bias);
      }
  }
}

// ---------------------------------------------------------------------------
// Output projection: out = ctx @ Wo^T + bo -> fp32 [4096,1024].
// ---------------------------------------------------------------------------
__global__ __launch_bounds__(256)
void outproj_kernel(const ushort* __restrict__ ctx, const ushort* __restrict__ Wo,
                    const float* __restrict__ bo, float* __restrict__ out) {
  __shared__ __align__(16) ushort As[128 * 32];
  __shared__ __align__(16) ushort Bs[128 * 32];
  const int n0 = blockIdx.x * 128;
  const int m0 = blockIdx.y * 128;

  f32x4 acc[4][4] = {};
  gemm_core(ctx, Wo, m0, n0, As, Bs, acc);

  const int lane = threadIdx.x & 63;
  const int wave = threadIdx.x >> 6;
  const int quad = lane >> 4, lrow = lane & 15;
  const int wm = wave >> 1, wn = wave & 1;
#pragma unroll
  for (int j = 0; j < 4; ++j) {
    const int col = n0 + wn * 64 + j * 16 + lrow;
    const float bias = bo[col];
#pragma unroll
    for (int i = 0; i < 4; ++i)
#pragma unroll
      for (int r = 0; r < 4; ++r) {
        const int row = m0 + wm * 64 + i * 16 + quad * 4 + r;
        out[((size_t)row << 10) + col] = acc[i][j][r] + bias;
      }
  }
}

// ---------------------------------------------------------------------------
// Causal flash attention (fp32 VALU). One block per (bh, 64-row q block).
// LDS tiles 64x64 fp32 with 16B-granule XOR swizzle; V stored transposed.
// ---------------------------------------------------------------------------
static __device__ __forceinline__ int tile_word(int row, int chunk) {
  return (row << 6) + (((chunk ^ row) & 15) << 2);
}

__global__ __launch_bounds__(256)
void attn_kernel(const ushort* __restrict__ qh, const ushort* __restrict__ kh,
                 const ushort* __restrict__ vh, ushort* __restrict__ ctx) {
  __shared__ __align__(16) float q_s[4096];
  __shared__ __align__(16) float kp_s[4096];   // K tile, then reused for P
  __shared__ __align__(16) float v_t[4096];    // V transposed [d][kk]
  const int tid = threadIdx.x;
  const int qb = blockIdx.x;        // q block 0..31
  const int bh = blockIdx.y;        // 0..31
  const int b = bh >> 4, h = bh & 15;
  const size_t base = (size_t)bh << 17;   // bh * S * D
  const int tr = tid >> 4, tc = tid & 15;

  // load Q tile, scaled by 1/sqrt(D)=0.125
#pragma unroll
  for (int p = 0; p < 4; ++p) {
    const int e0 = (p * 256 + tid) * 4;
    const int r = e0 >> 6, d0 = e0 & 63;
    const ushort4 uq = *(const ushort4*)(qh + base + ((size_t)(qb * 64 + r) << 6) + d0);
    f32x4 fq;
    fq[0] = bf2f(uq.x) * 0.125f; fq[1] = bf2f(uq.y) * 0.125f;
    fq[2] = bf2f(uq.z) * 0.125f; fq[3] = bf2f(uq.w) * 0.125f;
    *(f32x4*)&q_s[tile_word(r, d0 >> 2)] = fq;
  }

  float m_i[4], l_i[4], o_acc[4][4];
#pragma unroll
  for (int i = 0; i < 4; ++i) {
    m_i[i] = -1e30f; l_i[i] = 0.f;
#pragma unroll
    for (int j = 0; j < 4; ++j) o_acc[i][j] = 0.f;
  }

  for (int kt = 0; kt <= qb; ++kt) {
    __syncthreads();   // prior iteration's PV reads done (and q_s load on iter 0)
#pragma unroll
    for (int p = 0; p < 4; ++p) {
      const int e0 = (p * 256 + tid) * 4;
      const int r = e0 >> 6, d0 = e0 & 63;
      const size_t goff = base + ((size_t)(kt * 64 + r) << 6) + d0;
      const ushort4 uk = *(const ushort4*)(kh + goff);
      f32x4 fk;
      fk[0] = bf2f(uk.x); fk[1] = bf2f(uk.y); fk[2] = bf2f(uk.z); fk[3] = bf2f(uk.w);
      *(f32x4*)&kp_s[tile_word(r, d0 >> 2)] = fk;
      const ushort4 uv = *(const ushort4*)(vh + goff);
      v_t[tile_word(d0 + 0, r >> 2) + (r & 3)] = bf2f(uv.x);
      v_t[tile_word(d0 + 1, r >> 2) + (r & 3)] = bf2f(uv.y);
      v_t[tile_word(d0 + 2, r >> 2) + (r & 3)] = bf2f(uv.z);
      v_t[tile_word(d0 + 3, r >> 2) + (r & 3)] = bf2f(uv.w);
    }
    __syncthreads();

    // QK^T: s[i][j] = q_row(tr*4+i) . k_row(tc*4+j)
    float s[4][4] = {};
    for (int kc = 0; kc < 16; ++kc) {
      f32x4 qv[4], kv[4];
#pragma unroll
      for (int i = 0; i < 4; ++i) qv[i] = *(const f32x4*)&q_s[tile_word(tr * 4 + i, kc)];
#pragma unroll
      for (int j = 0; j < 4; ++j) kv[j] = *(const f32x4*)&kp_s[tile_word(tc * 4 + j, kc)];
#pragma unroll
      for (int i = 0; i < 4; ++i)
#pragma unroll
        for (int j = 0; j < 4; ++j)
          s[i][j] += qv[i][0] * kv[j][0] + qv[i][1] * kv[j][1] +
                     qv[i][2] * kv[j][2] + qv[i][3] * kv[j][3];
    }
    if (kt == qb) {  // causal mask on diagonal tile
#pragma unroll
      for (int i = 0; i < 4; ++i)
#pragma unroll
        for (int j = 0; j < 4; ++j)
          if (tc * 4 + j > tr * 4 + i) s[i][j] = -1e30f;
    }
    __syncthreads();   // everyone done reading kp_s (K) before P overwrites it

    // online softmax; write P into kp_s
#pragma unroll
    for (int i = 0; i < 4; ++i) {
      float tm = fmaxf(fmaxf(s[i][0], s[i][1]), fmaxf(s[i][2], s[i][3]));
#pragma unroll
      for (int off = 1; off < 16; off <<= 1) tm = fmaxf(tm, __shfl_xor(tm, off));
      const float mn = fmaxf(m_i[i], tm);
      const float alpha = __expf(m_i[i] - mn);
      m_i[i] = mn;
      float ps0 = __expf(s[i][0] - mn), ps1 = __expf(s[i][1] - mn);
      float ps2 = __expf(s[i][2] - mn), ps3 = __expf(s[i][3] - mn);
      float tl = ps0 + ps1 + ps2 + ps3;
#pragma unroll
      for (int off = 1; off < 16; off <<= 1) tl += __shfl_xor(tl, off);
      l_i[i] = l_i[i] * alpha + tl;
#pragma unroll
      for (int j = 0; j < 4; ++j) o_acc[i][j] *= alpha;
      f32x4 pv; pv[0] = ps0; pv[1] = ps1; pv[2] = ps2; pv[3] = ps3;
      *(f32x4*)&kp_s[tile_word(tr * 4 + i, tc)] = pv;
    }
    __syncthreads();   // P visible

    // PV: o[i][j] += sum_kk P[r_i][kk] * V[kk][d_j]
    for (int kc = 0; kc < 16; ++kc) {
      f32x4 pv[4], vv[4];
#pragma unroll
      for (int i = 0; i < 4; ++i) pv[i] = *(const f32x4*)&kp_s[tile_word(tr * 4 + i, kc)];
#pragma unroll
      for (int j = 0; j < 4; ++j) vv[j] = *(const f32x4*)&v_t[tile_word(tc * 4 + j, kc)];
#pragma unroll
      for (int i = 0; i < 4; ++i)
#pragma unroll
        for (int j = 0; j < 4; ++j)
          o_acc[i][j] += pv[i][0] * vv[j][0] + pv[i][1] * vv[j][1] +
                         pv[i][2] * vv[j][2] + pv[i][3] * vv[j][3];
    }
  }

  // write ctx bf16 [B,S,H*D]
#pragma unroll
  for (int i = 0; i < 4; ++i) {
    const float inv = 1.f / l_i[i];
    const int qi = qb * 64 + tr * 4 + i;
    ushort4 u;
    u.x = f2bf(o_acc[i][0] * inv);
    u.y = f2bf(o_acc[i][1] * inv);
    u.z = f2bf(o_acc[i][2] * inv);
    u.w = f2bf(o_acc[i][3] * inv);
    *(ushort4*)(ctx + ((size_t)((b << 11) + qi) << 10) + (h << 6) + tc * 4) = u;
  }
}

// ---------------------------------------------------------------------------
extern "C" void kernel_launch(void* const* d_in, const int* in_sizes, int n_in,
                              void* d_out, int out_size, void* d_ws, size_t ws_size,
                              hipStream_t stream) {
  const float* q  = (const float*)d_in[0];
  const float* k  = (const float*)d_in[1];
  const float* v  = (const float*)d_in[2];
  // d_in[3] = causal mask (tril) — applied analytically, not read
  const float* Wq = (const float*)d_in[4];
  const float* bq = (const float*)d_in[5];
  const float* Wk = (const float*)d_in[6];
  const float* bk = (const float*)d_in[7];
  const float* Wv = (const float*)d_in[8];
  const float* bv = (const float*)d_in[9];
  const float* Wo = (const float*)d_in[10];
  const float* bo = (const float*)d_in[11];

  const size_t NTOK = (size_t)PB * PS * PE;   // 4,194,304 elems
  const size_t NW   = (size_t)PE * PE;        // 1,048,576 elems
  ushort* qh  = (ushort*)d_ws;
  ushort* kh  = qh + NTOK;
  ushort* vh  = kh + NTOK;
  ushort* qc  = vh + NTOK;
  ushort* kc  = qc + NTOK;
  ushort* vc  = kc + NTOK;
  ushort* wqc = vc + NTOK;
  ushort* wkc = wqc + NW;
  ushort* wvc = wkc + NW;
  ushort* woc = wvc + NW;
  ushort* ctx = qc;   // alias: qc is dead after qkv_kernel completes

  cvt_kernel<<<dim3(2048, 7), dim3(256), 0, stream>>>(
      q, k, v, Wq, Wk, Wv, Wo, qc, kc, vc, wqc, wkc, wvc, woc);
  qkv_kernel<<<dim3(24, 32), dim3(256), 0, stream>>>(
      qc, kc, vc, wqc, wkc, wvc, bq, bk, bv, qh, kh, vh);
  attn_kernel<<<dim3(32, 32), dim3(256), 0, stream>>>(qh, kh, vh, ctx);
  outproj_kernel<<<dim3(8, 32), dim3(256), 0, stream>>>(
      ctx, woc, bo, (float*)d_out);
}

// Round 3
// 263.382 us; speedup vs baseline: 5.3640x; 5.3640x over previous
//
#include <hip/hip_runtime.h>
#include <hip/hip_bf16.h>
#include <cstdint>

// Problem dims (fixed): B=2, S=2048, E=1024, H=16, D=64
#define PB 2
#define PS 2048
#define PE 1024
#define PH 16
#define PD 64

typedef __attribute__((ext_vector_type(8))) short short8;
typedef __attribute__((ext_vector_type(8))) ushort u16x8;
typedef __attribute__((ext_vector_type(4))) float f32x4;

static __device__ __forceinline__ float bf2f(ushort u) {
  return __uint_as_float(((unsigned)u) << 16);
}
static __device__ __forceinline__ ushort f2bf(float f) {
  unsigned u = __float_as_uint(f);
  u += 0x7fffu + ((u >> 16) & 1u);   // RNE
  return (ushort)(u >> 16);
}

// CK-idiom async global->LDS 16B copy. LDS dest must be wave-uniform base.
static __device__ __forceinline__ void async16(void* lds, const void* g) {
  __attribute__((address_space(3))) unsigned* l =
      reinterpret_cast<__attribute__((address_space(3))) unsigned*>(
          reinterpret_cast<uintptr_t>(lds));
  const __attribute__((address_space(1))) unsigned* gp =
      reinterpret_cast<const __attribute__((address_space(1))) unsigned*>(
          reinterpret_cast<uintptr_t>(g));
  __builtin_amdgcn_global_load_lds(gp, l, 16, 0, 0);
}

// ---------------------------------------------------------------------------
// fp32 -> bf16 pre-conversion. blockIdx.y selects tensor.
// ---------------------------------------------------------------------------
__global__ __launch_bounds__(256)
void cvt_kernel(const float* __restrict__ s0, const float* __restrict__ s1,
                const float* __restrict__ s2, const float* __restrict__ s3,
                const float* __restrict__ s4, const float* __restrict__ s5,
                const float* __restrict__ s6,
                ushort* d0, ushort* d1, ushort* d2, ushort* d3, ushort* d4,
                ushort* d5, ushort* d6) {
  const int t = blockIdx.y;
  const float* src = t == 0 ? s0 : t == 1 ? s1 : t == 2 ? s2 : t == 3 ? s3
                   : t == 4 ? s4 : t == 5 ? s5 : s6;
  ushort* dst = t == 0 ? d0 : t == 1 ? d1 : t == 2 ? d2 : t == 3 ? d3
              : t == 4 ? d4 : t == 5 ? d5 : d6;
  const size_t n = (t < 3) ? (size_t)4194304 : (size_t)1048576;
  const size_t i0 = ((size_t)blockIdx.x * 256 + threadIdx.x) * 8;
  if (i0 >= n) return;
  const f32x4 a = *(const f32x4*)(src + i0);
  const f32x4 b = *(const f32x4*)(src + i0 + 4);
  u16x8 o;
  o[0] = f2bf(a[0]); o[1] = f2bf(a[1]); o[2] = f2bf(a[2]); o[3] = f2bf(a[3]);
  o[4] = f2bf(b[0]); o[5] = f2bf(b[1]); o[6] = f2bf(b[2]); o[7] = f2bf(b[3]);
  *(u16x8*)(dst + i0) = o;
}

// ---------------------------------------------------------------------------
// GEMM core (m97 structure): C[128x128] += A[M,K] * W[N,K]^T over K=1024.
// ---------------------------------------------------------------------------
__device__ __forceinline__ void gemm_core(const ushort* __restrict__ A,
                                          const ushort* __restrict__ W,
                                          int m0, int n0,
                                          ushort* As, ushort* Bs,
                                          f32x4 acc[4][4]) {
  const int tid  = threadIdx.x;
  const int wave = tid >> 6;
  const int lane = tid & 63;
  const int quad = lane >> 4;
  const int lrow = lane & 15;
  const int wm = wave >> 1;
  const int wn = wave & 1;
  const int row0 = tid >> 2;
  const int kc8  = (tid & 3) * 8;

  for (int kt = 0; kt < PE; kt += 32) {
    async16(As + (size_t)wave * 512,        A + (size_t)(m0 + row0)      * PE + kt + kc8);
    async16(As + 2048 + (size_t)wave * 512, A + (size_t)(m0 + row0 + 64) * PE + kt + kc8);
    async16(Bs + (size_t)wave * 512,        W + (size_t)(n0 + row0)      * PE + kt + kc8);
    async16(Bs + 2048 + (size_t)wave * 512, W + (size_t)(n0 + row0 + 64) * PE + kt + kc8);
    __syncthreads();
    short8 af[4], bf[4];
#pragma unroll
    for (int i = 0; i < 4; ++i) {
      af[i] = *(const short8*)(As + (wm * 64 + i * 16 + lrow) * 32 + quad * 8);
      bf[i] = *(const short8*)(Bs + (wn * 64 + i * 16 + lrow) * 32 + quad * 8);
    }
#pragma unroll
    for (int i = 0; i < 4; ++i)
#pragma unroll
      for (int j = 0; j < 4; ++j)
        acc[i][j] = __builtin_amdgcn_mfma_f32_16x16x32_bf16(af[i], bf[j], acc[i][j], 0, 0, 0);
    __syncthreads();
  }
}

// ---------------------------------------------------------------------------
// Fused QKV projection. Q,K -> bf16 [B,H,S,D]; V -> bf16 [B,H,D,S] (transposed
// so attention's PV B-operand stages key-contiguous).
// ---------------------------------------------------------------------------
__global__ __launch_bounds__(256)
void qkv_kernel(const ushort* __restrict__ q, const ushort* __restrict__ k,
                const ushort* __restrict__ v,
                const ushort* __restrict__ Wq, const ushort* __restrict__ Wk,
                const ushort* __restrict__ Wv,
                const float* __restrict__ bq, const float* __restrict__ bk,
                const float* __restrict__ bv,
                ushort* __restrict__ qh, ushort* __restrict__ kh,
                ushort* __restrict__ vt) {
  __shared__ __align__(16) ushort As[128 * 32];
  __shared__ __align__(16) ushort Bs[128 * 32];
  const int which = blockIdx.x >> 3;
  const int n0 = (blockIdx.x & 7) * 128;
  const int m0 = blockIdx.y * 128;
  const ushort* A  = which == 0 ? q  : (which == 1 ? k  : v);
  const ushort* W  = which == 0 ? Wq : (which == 1 ? Wk : Wv);
  const float* bi  = which == 0 ? bq : (which == 1 ? bk : bv);
  ushort* Out      = which == 0 ? qh : (which == 1 ? kh : vt);

  f32x4 acc[4][4] = {};
  gemm_core(A, W, m0, n0, As, Bs, acc);

  const int lane = threadIdx.x & 63;
  const int wave = threadIdx.x >> 6;
  const int quad = lane >> 4, lrow = lane & 15;
  const int wm = wave >> 1, wn = wave & 1;
  const bool vtrans = (which == 2);
#pragma unroll
  for (int j = 0; j < 4; ++j) {
    const int col = n0 + wn * 64 + j * 16 + lrow;          // n in [0,1024)
    const float bias = bi[col];
    const int h = col >> 6, d = col & 63;
#pragma unroll
    for (int i = 0; i < 4; ++i)
#pragma unroll
      for (int r = 0; r < 4; ++r) {
        const int row = m0 + wm * 64 + i * 16 + quad * 4 + r;  // m in [0,4096)
        const int b = row >> 11, s = row & 2047;
        const size_t bh = (size_t)((b << 4) + h) << 17;
        const size_t idx = vtrans ? (bh + ((size_t)d << 11) + s)
                                  : (bh + ((size_t)s << 6) + d);
        Out[idx] = f2bf(acc[i][j][r] + bias);
      }
  }
}

// ---------------------------------------------------------------------------
// Output projection: out = ctx @ Wo^T + bo -> fp32 [4096,1024].
// ---------------------------------------------------------------------------
__global__ __launch_bounds__(256)
void outproj_kernel(const ushort* __restrict__ ctx, const ushort* __restrict__ Wo,
                    const float* __restrict__ bo, float* __restrict__ out) {
  __shared__ __align__(16) ushort As[128 * 32];
  __shared__ __align__(16) ushort Bs[128 * 32];
  const int n0 = blockIdx.x * 128;
  const int m0 = blockIdx.y * 128;

  f32x4 acc[4][4] = {};
  gemm_core(ctx, Wo, m0, n0, As, Bs, acc);

  const int lane = threadIdx.x & 63;
  const int wave = threadIdx.x >> 6;
  const int quad = lane >> 4, lrow = lane & 15;
  const int wm = wave >> 1, wn = wave & 1;
#pragma unroll
  for (int j = 0; j < 4; ++j) {
    const int col = n0 + wn * 64 + j * 16 + lrow;
    const float bias = bo[col];
#pragma unroll
    for (int i = 0; i < 4; ++i)
#pragma unroll
      for (int r = 0; r < 4; ++r) {
        const int row = m0 + wm * 64 + i * 16 + quad * 4 + r;
        out[((size_t)row << 10) + col] = acc[i][j][r] + bias;
      }
  }
}

// ---------------------------------------------------------------------------
// MFMA causal flash attention. One block = (bh, q-tile pair {p, 31-p}), 256
// threads = 4 waves; each wave owns a 16-row q strip of the 64-row q tile.
// K tile [key][d] and V^T tile [d][key] staged in LDS (double-buffered) with
// XOR swizzle on 16B granules; P transposed through LDS as bf16.
// ---------------------------------------------------------------------------
#define SW_IDX(r, g) (((r) << 6) + ((((g) ^ ((r) & 7))) << 3))

__global__ __launch_bounds__(256)
void attn_kernel(const ushort* __restrict__ qh, const ushort* __restrict__ kh,
                 const ushort* __restrict__ vt, ushort* __restrict__ ctx) {
  __shared__ __align__(16) ushort Ks[2][4096];
  __shared__ __align__(16) ushort Vs[2][4096];
  __shared__ __align__(16) ushort Ps[4096];
  const int tid  = threadIdx.x;
  const int wave = tid >> 6;
  const int lane = tid & 63;
  const int quad = lane >> 4;
  const int lrow = lane & 15;
  const int bh = blockIdx.y, b = bh >> 4, h = bh & 15;
  const size_t base = (size_t)bh << 17;     // bh * S * D
  const int srow = tid >> 2;                // staging row 0..63
  const int sg0  = (tid & 3) * 2;           // staging granules sg0, sg0+1
  const int pr   = wave * 16 + lrow;        // this lane's q row (A-frag m)

#pragma unroll 1
  for (int half = 0; half < 2; ++half) {
    const int qb = (half == 0) ? blockIdx.x : 31 - blockIdx.x;
    const int q0 = qb * 64;

    // Q fragments (registers for the whole q tile), scaled by 1/sqrt(D)=0.125
    short8 qf0, qf1;
    {
      const ushort* qp = qh + base + (size_t)(q0 + pr) * 64 + quad * 8;
      const u16x8 a = *(const u16x8*)qp;
      const u16x8 c = *(const u16x8*)(qp + 32);
#pragma unroll
      for (int j = 0; j < 8; ++j) {
        qf0[j] = (short)f2bf(bf2f(a[j]) * 0.125f);
        qf1[j] = (short)f2bf(bf2f(c[j]) * 0.125f);
      }
    }

    f32x4 o_acc[4] = {};
    float m_i[4], l_i[4];
#pragma unroll
    for (int r = 0; r < 4; ++r) { m_i[r] = -1e30f; l_i[r] = 0.f; }

    // prefetch tile 0 into registers
    u16x8 kst0, kst1, vst0, vst1;
    {
      const ushort* kp = kh + base + (size_t)srow * 64 + sg0 * 8;
      kst0 = *(const u16x8*)kp; kst1 = *(const u16x8*)(kp + 8);
      const ushort* vp = vt + base + (size_t)srow * 2048 + sg0 * 8;
      vst0 = *(const u16x8*)vp; vst1 = *(const u16x8*)(vp + 8);
    }

    for (int kt = 0; kt <= qb; ++kt) {
      const int buf = kt & 1;
      // stage write (swizzled)
      *(u16x8*)&Ks[buf][SW_IDX(srow, sg0)]     = kst0;
      *(u16x8*)&Ks[buf][SW_IDX(srow, sg0 + 1)] = kst1;
      *(u16x8*)&Vs[buf][SW_IDX(srow, sg0)]     = vst0;
      *(u16x8*)&Vs[buf][SW_IDX(srow, sg0 + 1)] = vst1;
      __syncthreads();   // barrier A: tiles visible; prev PV fully done

      if (kt < qb) {     // early-issue next tile's global loads
        const ushort* kp = kh + base + (size_t)((kt + 1) * 64 + srow) * 64 + sg0 * 8;
        kst0 = *(const u16x8*)kp; kst1 = *(const u16x8*)(kp + 8);
        const ushort* vp = vt + base + (size_t)srow * 2048 + (kt + 1) * 64 + sg0 * 8;
        vst0 = *(const u16x8*)vp; vst1 = *(const u16x8*)(vp + 8);
      }

      // QK^T: S strip 16q x 64key, reduce over d=64 (2 k-steps)
      f32x4 s_acc[4] = {};
#pragma unroll
      for (int nt = 0; nt < 4; ++nt) {
        const int r = nt * 16 + lrow;       // key row in K tile (B-frag n)
        const short8 kb0 = *(const short8*)&Ks[buf][SW_IDX(r, quad)];
        const short8 kb1 = *(const short8*)&Ks[buf][SW_IDX(r, quad + 4)];
        s_acc[nt] = __builtin_amdgcn_mfma_f32_16x16x32_bf16(qf0, kb0, s_acc[nt], 0, 0, 0);
        s_acc[nt] = __builtin_amdgcn_mfma_f32_16x16x32_bf16(qf1, kb1, s_acc[nt], 0, 0, 0);
      }

      if (kt == qb) {    // causal mask on diagonal tile (local coords)
#pragma unroll
        for (int nt = 0; nt < 4; ++nt)
#pragma unroll
          for (int r = 0; r < 4; ++r)
            if (nt * 16 + lrow > wave * 16 + quad * 4 + r) s_acc[nt][r] = -1e30f;
      }

      // online softmax (rows = quad*4+reg within wave strip)
      float p[4][4];
#pragma unroll
      for (int r = 0; r < 4; ++r) {
        float rm = fmaxf(fmaxf(s_acc[0][r], s_acc[1][r]),
                         fmaxf(s_acc[2][r], s_acc[3][r]));
        rm = fmaxf(rm, __shfl_xor(rm, 1));
        rm = fmaxf(rm, __shfl_xor(rm, 2));
        rm = fmaxf(rm, __shfl_xor(rm, 4));
        rm = fmaxf(rm, __shfl_xor(rm, 8));
        const float mn = fmaxf(m_i[r], rm);
        const float alpha = __expf(m_i[r] - mn);
        m_i[r] = mn;
        float rs = 0.f;
#pragma unroll
        for (int nt = 0; nt < 4; ++nt) {
          p[nt][r] = __expf(s_acc[nt][r] - mn);
          rs += p[nt][r];
        }
        rs += __shfl_xor(rs, 1);
        rs += __shfl_xor(rs, 2);
        rs += __shfl_xor(rs, 4);
        rs += __shfl_xor(rs, 8);
        l_i[r] = l_i[r] * alpha + rs;
#pragma unroll
        for (int nt = 0; nt < 4; ++nt) o_acc[nt][r] *= alpha;
      }

      // P -> LDS (bf16), C-layout -> A-layout transform
#pragma unroll
      for (int nt = 0; nt < 4; ++nt) {
        const int gk = nt * 2 + (lrow >> 3);
#pragma unroll
        for (int r = 0; r < 4; ++r) {
          const int ql = wave * 16 + quad * 4 + r;
          Ps[(ql << 6) + (((gk ^ (ql & 7))) << 3) + (lrow & 7)] = f2bf(p[nt][r]);
        }
      }
      __syncthreads();   // barrier B: P visible

      // PV: O strip 16q x 64d, reduce over keys=64 (2 k-steps)
      const short8 pa0 = *(const short8*)&Ps[SW_IDX(pr, quad)];
      const short8 pa1 = *(const short8*)&Ps[SW_IDX(pr, quad + 4)];
#pragma unroll
      for (int nt = 0; nt < 4; ++nt) {
        const int r = nt * 16 + lrow;       // d row in V^T tile (B-frag n)
        const short8 vb0 = *(const short8*)&Vs[buf][SW_IDX(r, quad)];
        const short8 vb1 = *(const short8*)&Vs[buf][SW_IDX(r, quad + 4)];
        o_acc[nt] = __builtin_amdgcn_mfma_f32_16x16x32_bf16(pa0, vb0, o_acc[nt], 0, 0, 0);
        o_acc[nt] = __builtin_amdgcn_mfma_f32_16x16x32_bf16(pa1, vb1, o_acc[nt], 0, 0, 0);
      }
    }

    // epilogue: ctx [B,S,E] bf16
#pragma unroll
    for (int r = 0; r < 4; ++r) {
      const float inv = 1.f / l_i[r];
      const int s = q0 + wave * 16 + quad * 4 + r;
      const size_t rowb = ((size_t)b << 21) + ((size_t)s << 10) + (h << 6);
#pragma unroll
      for (int nt = 0; nt < 4; ++nt)
        ctx[rowb + nt * 16 + lrow] = f2bf(o_acc[nt][r] * inv);
    }
    __syncthreads();   // protect LDS before next half re-stages
  }
}

// ---------------------------------------------------------------------------
extern "C" void kernel_launch(void* const* d_in, const int* in_sizes, int n_in,
                              void* d_out, int out_size, void* d_ws, size_t ws_size,
                              hipStream_t stream) {
  const float* q  = (const float*)d_in[0];
  const float* k  = (const float*)d_in[1];
  const float* v  = (const float*)d_in[2];
  // d_in[3] = causal mask (tril) — applied analytically, not read
  const float* Wq = (const float*)d_in[4];
  const float* bq = (const float*)d_in[5];
  const float* Wk = (const float*)d_in[6];
  const float* bk = (const float*)d_in[7];
  const float* Wv = (const float*)d_in[8];
  const float* bv = (const float*)d_in[9];
  const float* Wo = (const float*)d_in[10];
  const float* bo = (const float*)d_in[11];

  const size_t NTOK = (size_t)PB * PS * PE;   // 4,194,304 elems
  const size_t NW   = (size_t)PE * PE;        // 1,048,576 elems
  ushort* qh  = (ushort*)d_ws;
  ushort* kh  = qh + NTOK;
  ushort* vt  = kh + NTOK;
  ushort* qc  = vt + NTOK;
  ushort* kc  = qc + NTOK;
  ushort* vc  = kc + NTOK;
  ushort* wqc = vc + NTOK;
  ushort* wkc = wqc + NW;
  ushort* wvc = wkc + NW;
  ushort* woc = wvc + NW;
  ushort* ctx = qc;   // alias: qc is dead after qkv_kernel completes

  cvt_kernel<<<dim3(2048, 7), dim3(256), 0, stream>>>(
      q, k, v, Wq, Wk, Wv, Wo, qc, kc, vc, wqc, wkc, wvc, woc);
  qkv_kernel<<<dim3(24, 32), dim3(256), 0, stream>>>(
      qc, kc, vc, wqc, wkc, wvc, bq, bk, bv, qh, kh, vt);
  attn_kernel<<<dim3(16, 32), dim3(256), 0, stream>>>(qh, kh, vt, ctx);
  outproj_kernel<<<dim3(8, 32), dim3(256), 0, stream>>>(
      ctx, woc, bo, (float*)d_out);
}

// Round 5
// 254.478 us; speedup vs baseline: 5.5517x; 1.0350x over previous
//
#include <hip/hip_runtime.h>
#include <hip/hip_bf16.h>
#include <cstdint>

// Problem dims (fixed): B=2, S=2048, E=1024, H=16, D=64
#define PB 2
#define PS 2048
#define PE 1024
#define PH 16
#define PD 64

typedef __attribute__((ext_vector_type(8))) short short8;
typedef __attribute__((ext_vector_type(8))) ushort u16x8;
typedef __attribute__((ext_vector_type(4))) float f32x4;

static __device__ __forceinline__ float bf2f(ushort u) {
  return __uint_as_float(((unsigned)u) << 16);
}
static __device__ __forceinline__ ushort f2bf(float f) {
  unsigned u = __float_as_uint(f);
  u += 0x7fffu + ((u >> 16) & 1u);   // RNE
  return (ushort)(u >> 16);
}

// CK-idiom async global->LDS 16B copy. LDS dest must be wave-uniform base.
static __device__ __forceinline__ void async16(void* lds, const void* g) {
  __attribute__((address_space(3))) unsigned* l =
      reinterpret_cast<__attribute__((address_space(3))) unsigned*>(
          reinterpret_cast<uintptr_t>(lds));
  const __attribute__((address_space(1))) unsigned* gp =
      reinterpret_cast<const __attribute__((address_space(1))) unsigned*>(
          reinterpret_cast<uintptr_t>(g));
  __builtin_amdgcn_global_load_lds(gp, l, 16, 0, 0);
}

// ---------------------------------------------------------------------------
// fp32 -> bf16 pre-conversion. blockIdx.y selects tensor.
// ---------------------------------------------------------------------------
__global__ __launch_bounds__(256)
void cvt_kernel(const float* __restrict__ s0, const float* __restrict__ s1,
                const float* __restrict__ s2, const float* __restrict__ s3,
                const float* __restrict__ s4, const float* __restrict__ s5,
                const float* __restrict__ s6,
                ushort* d0, ushort* d1, ushort* d2, ushort* d3, ushort* d4,
                ushort* d5, ushort* d6) {
  const int t = blockIdx.y;
  const float* src = t == 0 ? s0 : t == 1 ? s1 : t == 2 ? s2 : t == 3 ? s3
                   : t == 4 ? s4 : t == 5 ? s5 : s6;
  ushort* dst = t == 0 ? d0 : t == 1 ? d1 : t == 2 ? d2 : t == 3 ? d3
              : t == 4 ? d4 : t == 5 ? d5 : d6;
  const size_t n = (t < 3) ? (size_t)4194304 : (size_t)1048576;
  const size_t i0 = ((size_t)blockIdx.x * 256 + threadIdx.x) * 8;
  if (i0 >= n) return;
  const f32x4 a = *(const f32x4*)(src + i0);
  const f32x4 b = *(const f32x4*)(src + i0 + 4);
  u16x8 o;
  o[0] = f2bf(a[0]); o[1] = f2bf(a[1]); o[2] = f2bf(a[2]); o[3] = f2bf(a[3]);
  o[4] = f2bf(b[0]); o[5] = f2bf(b[1]); o[6] = f2bf(b[2]); o[7] = f2bf(b[3]);
  *(u16x8*)(dst + i0) = o;
}

// ---------------------------------------------------------------------------
// GEMM core (m97 structure): BM=BN=128, BK=32, 256 threads, 4 waves 2x2.
// SWAP=false: acc[i][j] = C[m=x-rows i][n=W-rows j] (normal).
// SWAP=true : acc[i][j] = C[m=W-rows j][n=x-rows i] (transposed output).
// ---------------------------------------------------------------------------
template <bool SWAP>
__device__ __forceinline__ void gemm_core(const ushort* __restrict__ A,
                                          const ushort* __restrict__ W,
                                          int m0, int n0,
                                          ushort* As, ushort* Bs,
                                          f32x4 acc[4][4]) {
  const int tid  = threadIdx.x;
  const int wave = tid >> 6;
  const int lane = tid & 63;
  const int quad = lane >> 4;
  const int lrow = lane & 15;
  const int wm = wave >> 1;
  const int wn = wave & 1;
  const int row0 = tid >> 2;
  const int kc8  = (tid & 3) * 8;

  for (int kt = 0; kt < PE; kt += 32) {
    async16(As + (size_t)wave * 512,        A + (size_t)(m0 + row0)      * PE + kt + kc8);
    async16(As + 2048 + (size_t)wave * 512, A + (size_t)(m0 + row0 + 64) * PE + kt + kc8);
    async16(Bs + (size_t)wave * 512,        W + (size_t)(n0 + row0)      * PE + kt + kc8);
    async16(Bs + 2048 + (size_t)wave * 512, W + (size_t)(n0 + row0 + 64) * PE + kt + kc8);
    __syncthreads();
    short8 af[4], bf[4];
#pragma unroll
    for (int i = 0; i < 4; ++i) {
      af[i] = *(const short8*)(As + (wm * 64 + i * 16 + lrow) * 32 + quad * 8);
      bf[i] = *(const short8*)(Bs + (wn * 64 + i * 16 + lrow) * 32 + quad * 8);
    }
#pragma unroll
    for (int i = 0; i < 4; ++i)
#pragma unroll
      for (int j = 0; j < 4; ++j) {
        if (SWAP)
          acc[i][j] = __builtin_amdgcn_mfma_f32_16x16x32_bf16(bf[j], af[i], acc[i][j], 0, 0, 0);
        else
          acc[i][j] = __builtin_amdgcn_mfma_f32_16x16x32_bf16(af[i], bf[j], acc[i][j], 0, 0, 0);
      }
    __syncthreads();
  }
}

// ---------------------------------------------------------------------------
// Fused QKV projection. Q,K -> bf16 [B,H,S,D]; V -> bf16 [B,H,D,S] via
// operand-swapped MFMA (V^T comes out directly in C-layout -> coalesced-ish
// stores: 16 consecutive s per row cluster instead of 2B scatter).
// ---------------------------------------------------------------------------
__global__ __launch_bounds__(256)
void qkv_kernel(const ushort* __restrict__ q, const ushort* __restrict__ k,
                const ushort* __restrict__ v,
                const ushort* __restrict__ Wq, const ushort* __restrict__ Wk,
                const ushort* __restrict__ Wv,
                const float* __restrict__ bq, const float* __restrict__ bk,
                const float* __restrict__ bv,
                ushort* __restrict__ qh, ushort* __restrict__ kh,
                ushort* __restrict__ vt) {
  __shared__ __align__(16) ushort As[128 * 32];
  __shared__ __align__(16) ushort Bs[128 * 32];
  const int which = blockIdx.x >> 3;
  const int n0 = (blockIdx.x & 7) * 128;
  const int m0 = blockIdx.y * 128;
  const ushort* A  = which == 0 ? q  : (which == 1 ? k  : v);
  const ushort* W  = which == 0 ? Wq : (which == 1 ? Wk : Wv);
  const float* bi  = which == 0 ? bq : (which == 1 ? bk : bv);

  const int lane = threadIdx.x & 63;
  const int wave = threadIdx.x >> 6;
  const int quad = lane >> 4, lrow = lane & 15;
  const int wm = wave >> 1, wn = wave & 1;

  f32x4 acc[4][4] = {};
  if (which == 2) {
    gemm_core<true>(A, W, m0, n0, As, Bs, acc);
    // acc[i][j]: C[m=W-row tile j][n=x-row tile i]; col=lane&15 -> x-row,
    // row=quad*4+r -> W-row (d-col). Store V^T [B,H,D,S].
#pragma unroll
    for (int j = 0; j < 4; ++j) {
#pragma unroll
      for (int i = 0; i < 4; ++i) {
        const int xrow = m0 + wm * 64 + i * 16 + lrow;
        const int b = xrow >> 11, s = xrow & 2047;
#pragma unroll
        for (int r = 0; r < 4; ++r) {
          const int dcol = n0 + wn * 64 + j * 16 + quad * 4 + r;
          const int h = dcol >> 6, d = dcol & 63;
          vt[((size_t)((b << 4) + h) << 17) + ((size_t)d << 11) + s] =
              f2bf(acc[i][j][r] + bi[dcol]);
        }
      }
    }
  } else {
    gemm_core<false>(A, W, m0, n0, As, Bs, acc);
    ushort* Out = which == 0 ? qh : kh;
#pragma unroll
    for (int j = 0; j < 4; ++j) {
      const int col = n0 + wn * 64 + j * 16 + lrow;          // n in [0,1024)
      const float bias = bi[col];
      const int h = col >> 6, d = col & 63;
#pragma unroll
      for (int i = 0; i < 4; ++i)
#pragma unroll
        for (int r = 0; r < 4; ++r) {
          const int row = m0 + wm * 64 + i * 16 + quad * 4 + r;  // m in [0,4096)
          const int b = row >> 11, s = row & 2047;
          Out[((size_t)((b << 4) + h) << 17) + ((size_t)s << 6) + d] =
              f2bf(acc[i][j][r] + bias);
        }
    }
  }
}

// ---------------------------------------------------------------------------
// Output projection: out = ctx @ Wo^T + bo -> fp32 [4096,1024].
// ---------------------------------------------------------------------------
__global__ __launch_bounds__(256)
void outproj_kernel(const ushort* __restrict__ ctx, const ushort* __restrict__ Wo,
                    const float* __restrict__ bo, float* __restrict__ out) {
  __shared__ __align__(16) ushort As[128 * 32];
  __shared__ __align__(16) ushort Bs[128 * 32];
  const int n0 = blockIdx.x * 128;
  const int m0 = blockIdx.y * 128;

  f32x4 acc[4][4] = {};
  gemm_core<false>(ctx, Wo, m0, n0, As, Bs, acc);

  const int lane = threadIdx.x & 63;
  const int wave = threadIdx.x >> 6;
  const int quad = lane >> 4, lrow = lane & 15;
  const int wm = wave >> 1, wn = wave & 1;
#pragma unroll
  for (int j = 0; j < 4; ++j) {
    const int col = n0 + wn * 64 + j * 16 + lrow;
    const float bias = bo[col];
#pragma unroll
    for (int i = 0; i < 4; ++i)
#pragma unroll
      for (int r = 0; r < 4; ++r) {
        const int row = m0 + wm * 64 + i * 16 + quad * 4 + r;
        out[((size_t)row << 10) + col] = acc[i][j][r] + bias;
      }
  }
}

// ---------------------------------------------------------------------------
// MFMA causal flash attention, S^T formulation. One block = (bh, q-tile pair
// {p, 31-p}), 4 waves x 16 q-rows. QK^T computed as mfma(K_frag, Q_frag) ->
// S^T: each lane owns one q-row (lane&15) x 16 keys (quad*4+reg per nt) ->
// scalar m/l, 2-shuffle reductions, b64 P writes into wave-private LDS
// (no P barrier). PV as mfma(Vt_frag, P_frag) -> O^T -> packed ushort4 stores.
// ---------------------------------------------------------------------------
#define SW_IDX(r, g) (((r) << 6) + ((((g) ^ ((r) & 7))) << 3))
#define QSCALE 0.180336879f   /* 1/sqrt(64) * log2(e) */

__global__ __launch_bounds__(256)
void attn_kernel(const ushort* __restrict__ qh, const ushort* __restrict__ kh,
                 const ushort* __restrict__ vt, ushort* __restrict__ ctx) {
  __shared__ __align__(16) ushort Ks[2][4096];
  __shared__ __align__(16) ushort Vs[2][4096];
  __shared__ __align__(16) ushort Ps[4][1024];   // wave-private 16q x 64k
  const int tid  = threadIdx.x;
  const int wave = tid >> 6;
  const int lane = tid & 63;
  const int quad = lane >> 4;
  const int lrow = lane & 15;
  const int bh = blockIdx.y, b = bh >> 4, h = bh & 15;
  const size_t base = (size_t)bh << 17;     // bh * S * D
  const int srow = tid >> 2;                // staging row 0..63
  const int sg0  = (tid & 3) * 2;           // staging granules sg0, sg0+1
  const int pr   = wave * 16 + lrow;        // this lane's q row in tile
  ushort* Pw = &Ps[wave][0];
  const int prow = lrow << 6;               // P row base (elements)

#pragma unroll 1
  for (int half = 0; half < 2; ++half) {
    const int qb = (half == 0) ? blockIdx.x : 31 - blockIdx.x;
    const int q0 = qb * 64;

    // Q B-fragments in registers, scaled by 1/sqrt(D)*log2(e)
    short8 qf0, qf1;
    {
      const ushort* qp = qh + base + (size_t)(q0 + pr) * 64 + quad * 8;
      const u16x8 a = *(const u16x8*)qp;
      const u16x8 c = *(const u16x8*)(qp + 32);
#pragma unroll
      for (int j = 0; j < 8; ++j) {
        qf0[j] = (short)f2bf(bf2f(a[j]) * QSCALE);
        qf1[j] = (short)f2bf(bf2f(c[j]) * QSCALE);
      }
    }

    f32x4 o_acc[4] = {};
    float m_i = -1e30f, l_i = 0.f;

    // prefetch tile 0 into registers
    u16x8 kst0, kst1, vst0, vst1;
    {
      const ushort* kp = kh + base + (size_t)srow * 64 + sg0 * 8;
      kst0 = *(const u16x8*)kp; kst1 = *(const u16x8*)(kp + 8);
      const ushort* vp = vt + base + (size_t)srow * 2048 + sg0 * 8;
      vst0 = *(const u16x8*)vp; vst1 = *(const u16x8*)(vp + 8);
    }

    for (int kt = 0; kt <= qb; ++kt) {
      const int buf = kt & 1;
      *(u16x8*)&Ks[buf][SW_IDX(srow, sg0)]     = kst0;
      *(u16x8*)&Ks[buf][SW_IDX(srow, sg0 + 1)] = kst1;
      *(u16x8*)&Vs[buf][SW_IDX(srow, sg0)]     = vst0;
      *(u16x8*)&Vs[buf][SW_IDX(srow, sg0 + 1)] = vst1;
      __syncthreads();   // single barrier per tile (double-buffered K/V)

      if (kt < qb) {     // early-issue next tile's global loads
        const ushort* kp = kh + base + (size_t)((kt + 1) * 64 + srow) * 64 + sg0 * 8;
        kst0 = *(const u16x8*)kp; kst1 = *(const u16x8*)(kp + 8);
        const ushort* vp = vt + base + (size_t)srow * 2048 + (kt + 1) * 64 + sg0 * 8;
        vst0 = *(const u16x8*)vp; vst1 = *(const u16x8*)(vp + 8);
      }

      // S^T = mfma(K, Q): lane -> q=pr, keys nt*16+quad*4+r
      f32x4 st[4] = {};
#pragma unroll
      for (int nt = 0; nt < 4; ++nt) {
        const int r = nt * 16 + lrow;
        const short8 kb0 = *(const short8*)&Ks[buf][SW_IDX(r, quad)];
        const short8 kb1 = *(const short8*)&Ks[buf][SW_IDX(r, quad + 4)];
        st[nt] = __builtin_amdgcn_mfma_f32_16x16x32_bf16(kb0, qf0, st[nt], 0, 0, 0);
        st[nt] = __builtin_amdgcn_mfma_f32_16x16x32_bf16(kb1, qf1, st[nt], 0, 0, 0);
      }

      if (kt == qb) {    // causal mask on diagonal tile (local coords)
#pragma unroll
        for (int nt = 0; nt < 4; ++nt)
#pragma unroll
          for (int r = 0; r < 4; ++r)
            if (nt * 16 + quad * 4 + r > pr) st[nt][r] = -1e30f;
      }

      // online softmax, scores in log2 domain; per-lane scalar state
      float rm = -1e30f;
#pragma unroll
      for (int nt = 0; nt < 4; ++nt)
#pragma unroll
        for (int r = 0; r < 4; ++r) rm = fmaxf(rm, st[nt][r]);
      rm = fmaxf(rm, __shfl_xor(rm, 16));
      rm = fmaxf(rm, __shfl_xor(rm, 32));
      const float mn = fmaxf(m_i, rm);
      const float alpha = exp2f(m_i - mn);
      m_i = mn;
      float rs = 0.f;
#pragma unroll
      for (int nt = 0; nt < 4; ++nt) {
        ushort4 pk;
        float p0 = exp2f(st[nt][0] - mn);
        float p1 = exp2f(st[nt][1] - mn);
        float p2 = exp2f(st[nt][2] - mn);
        float p3 = exp2f(st[nt][3] - mn);
        rs += (p0 + p1) + (p2 + p3);
        pk.x = f2bf(p0); pk.y = f2bf(p1); pk.z = f2bf(p2); pk.w = f2bf(p3);
        // keys nt*16+quad*4+[0..3]; granule = nt*2+(quad>>1), offs (quad&1)*4
        *(ushort4*)&Pw[prow + (((nt * 2 + (quad >> 1)) ^ (lrow & 7)) << 3) +
                       (quad & 1) * 4] = pk;
      }
      rs += __shfl_xor(rs, 16);
      rs += __shfl_xor(rs, 32);
      l_i = l_i * alpha + rs;
#pragma unroll
      for (int nt = 0; nt < 4; ++nt) o_acc[nt] *= alpha;

      // PV: O^T = mfma(V^T, P): lane -> q=pr, d = nt*16+quad*4+r
      const short8 pa0 = *(const short8*)&Pw[prow + ((quad ^ (lrow & 7)) << 3)];
      const short8 pa1 = *(const short8*)&Pw[prow + (((quad + 4) ^ (lrow & 7)) << 3)];
#pragma unroll
      for (int nt = 0; nt < 4; ++nt) {
        const int r = nt * 16 + lrow;
        const short8 vb0 = *(const short8*)&Vs[buf][SW_IDX(r, quad)];
        const short8 vb1 = *(const short8*)&Vs[buf][SW_IDX(r, quad + 4)];
        o_acc[nt] = __builtin_amdgcn_mfma_f32_16x16x32_bf16(vb0, pa0, o_acc[nt], 0, 0, 0);
        o_acc[nt] = __builtin_amdgcn_mfma_f32_16x16x32_bf16(vb1, pa1, o_acc[nt], 0, 0, 0);
      }
    }

    // epilogue: ctx [B,S,E] bf16, packed 8B stores
    const float inv = 1.f / l_i;
    const size_t rowb = ((size_t)b << 21) + ((size_t)(q0 + pr) << 10) + (h << 6);
#pragma unroll
    for (int nt = 0; nt < 4; ++nt) {
      ushort4 u;
      u.x = f2bf(o_acc[nt][0] * inv);
      u.y = f2bf(o_acc[nt][1] * inv);
      u.z = f2bf(o_acc[nt][2] * inv);
      u.w = f2bf(o_acc[nt][3] * inv);
      *(ushort4*)(ctx + rowb + nt * 16 + quad * 4) = u;
    }
    __syncthreads();   // protect LDS before next half re-stages
  }
}

// ---------------------------------------------------------------------------
extern "C" void kernel_launch(void* const* d_in, const int* in_sizes, int n_in,
                              void* d_out, int out_size, void* d_ws, size_t ws_size,
                              hipStream_t stream) {
  const float* q  = (const float*)d_in[0];
  const float* k  = (const float*)d_in[1];
  const float* v  = (const float*)d_in[2];
  // d_in[3] = causal mask (tril) — applied analytically, not read
  const float* Wq = (const float*)d_in[4];
  const float* bq = (const float*)d_in[5];
  const float* Wk = (const float*)d_in[6];
  const float* bk = (const float*)d_in[7];
  const float* Wv = (const float*)d_in[8];
  const float* bv = (const float*)d_in[9];
  const float* Wo = (const float*)d_in[10];
  const float* bo = (const float*)d_in[11];

  const size_t NTOK = (size_t)PB * PS * PE;   // 4,194,304 elems
  const size_t NW   = (size_t)PE * PE;        // 1,048,576 elems
  ushort* qh  = (ushort*)d_ws;
  ushort* kh  = qh + NTOK;
  ushort* vt  = kh + NTOK;
  ushort* qc  = vt + NTOK;
  ushort* kc  = qc + NTOK;
  ushort* vc  = kc + NTOK;
  ushort* wqc = vc + NTOK;
  ushort* wkc = wqc + NW;
  ushort* wvc = wkc + NW;
  ushort* woc = wvc + NW;
  ushort* ctx = qc;   // alias: qc is dead after qkv_kernel completes

  cvt_kernel<<<dim3(2048, 7), dim3(256), 0, stream>>>(
      q, k, v, Wq, Wk, Wv, Wo, qc, kc, vc, wqc, wkc, wvc, woc);
  qkv_kernel<<<dim3(24, 32), dim3(256), 0, stream>>>(
      qc, kc, vc, wqc, wkc, wvc, bq, bk, bv, qh, kh, vt);
  attn_kernel<<<dim3(16, 32), dim3(256), 0, stream>>>(qh, kh, vt, ctx);
  outproj_kernel<<<dim3(8, 32), dim3(256), 0, stream>>>(
      ctx, woc, bo, (float*)d_out);
}